// Round 1
// baseline (2962.878 us; speedup 1.0000x reference)
//
#include <hip/hip_runtime.h>

#define HID    256
#define N_ENT  100000
#define TOT_E  640000
#define HALF_E 320000
#define BN_EPSF 1e-5f

// ---------------- degree kernel ----------------
__global__ void deg_kernel(const int* __restrict__ ei, float* deg_in, float* deg_out) {
    int j = blockIdx.x * 256 + threadIdx.x;
    if (j >= TOT_E) return;
    int row = ei[j];                       // edge_index[0, j]
    atomicAdd((j < HALF_E ? deg_in : deg_out) + row, 1.0f);
}

// ---------------- edge scatter: acc[row] += norm * x[col] * rel[t] ----------------
__global__ __launch_bounds__(256) void scatter_kernel(
        const float* __restrict__ x, const int* __restrict__ ei,
        const int* __restrict__ et, const float* __restrict__ rel,
        const float* __restrict__ deg_in, const float* __restrict__ deg_out,
        float* __restrict__ accA, float* __restrict__ accB) {
    int edge = blockIdx.x * 4 + (threadIdx.x >> 6);
    if (edge >= TOT_E) return;
    int lane = threadIdx.x & 63;
    bool is_in = edge < HALF_E;
    int row = ei[edge];
    int col = ei[TOT_E + edge];
    int t   = et[edge];
    const float* deg = is_in ? deg_in : deg_out;
    float dr = deg[row], dc = deg[col];
    float norm = (dr > 0.f ? rsqrtf(dr) : 0.f) * (dc > 0.f ? rsqrtf(dc) : 0.f);
    float* acc = (is_in ? accA : accB) + (size_t)row * HID + lane * 4;
    float4 xv = *(const float4*)(x   + (size_t)col * HID + lane * 4);
    float4 rv = *(const float4*)(rel + (size_t)t   * HID + lane * 4);
    atomicAdd(acc + 0, xv.x * rv.x * norm);
    atomicAdd(acc + 1, xv.y * rv.y * norm);
    atomicAdd(acc + 2, xv.z * rv.z * norm);
    atomicAdd(acc + 3, xv.w * rv.w * norm);
}

// ---------------- fused GEMM: out = [accA|accB|x*loop_rel] @ [w_in;w_out;w_loop] / 3 ----------------
// block: 256 threads, computes 64 rows x 256 cols. K = 768 virtual, K-tile 32.
// AsT[k][row] transposed A tile (pad 68). Ws granule-swizzled [k][j][t].
__global__ __launch_bounds__(256) void fused_gemm(
        const float* __restrict__ accA, const float* __restrict__ accB,
        const float* __restrict__ x, const float* __restrict__ loop_rel,
        const float* __restrict__ w_in, const float* __restrict__ w_out,
        const float* __restrict__ w_loop, float* __restrict__ out)
{
    __shared__ float  AsT[32][68];      // [k][row]
    __shared__ float4 Ws[32][4][16];    // [k][j][t] -> cols 16t + 4j .. +3
    const int tid = threadIdx.x;
    const int r0  = blockIdx.x * 64;
    const int tr  = (tid >> 4) << 2;    // 0..60, 4 rows per thread
    const int tt  = tid & 15;           // column group (16 cols)
    float acc[4][16];
    #pragma unroll
    for (int u = 0; u < 4; ++u)
        #pragma unroll
        for (int j = 0; j < 16; ++j) acc[u][j] = 0.f;

    for (int kt = 0; kt < 24; ++kt) {
        const int src = kt >> 3;
        const int ks  = (kt & 7) << 5;
        const float* A = (src == 0) ? accA : ((src == 1) ? accB : x);
        const float* W = (src == 0) ? w_in : ((src == 1) ? w_out : w_loop);
        __syncthreads();
        // A tile: 64 rows x 32 k  (512 float4, 2 per thread)
        #pragma unroll
        for (int i = 0; i < 2; ++i) {
            int f = tid + (i << 8);
            int row = f >> 3;
            int cf  = f & 7;
            int gr  = r0 + row;
            float4 v = make_float4(0.f, 0.f, 0.f, 0.f);
            if (gr < N_ENT) v = *(const float4*)(A + (size_t)gr * HID + ks + (cf << 2));
            if (src == 2) {
                float4 lr = *(const float4*)(loop_rel + ks + (cf << 2));
                v.x *= lr.x; v.y *= lr.y; v.z *= lr.z; v.w *= lr.w;
            }
            int k = cf << 2;
            AsT[k + 0][row] = v.x;
            AsT[k + 1][row] = v.y;
            AsT[k + 2][row] = v.z;
            AsT[k + 3][row] = v.w;
        }
        // W tile: 32 k x 256 cols (2048 float4, 8 per thread), granule swizzle
        #pragma unroll
        for (int i = 0; i < 8; ++i) {
            int f  = tid + (i << 8);
            int kk = f >> 6;
            int g  = f & 63;
            float4 wv = *(const float4*)(W + (size_t)(ks + kk) * HID + (g << 2));
            Ws[kk][g & 3][g >> 2] = wv;
        }
        __syncthreads();
        #pragma unroll
        for (int kk = 0; kk < 32; ++kk) {
            float4 av = *(const float4*)(&AsT[kk][tr]);
            #pragma unroll
            for (int j = 0; j < 4; ++j) {
                float4 bv = Ws[kk][j][tt];
                acc[0][4*j+0] += av.x * bv.x; acc[0][4*j+1] += av.x * bv.y;
                acc[0][4*j+2] += av.x * bv.z; acc[0][4*j+3] += av.x * bv.w;
                acc[1][4*j+0] += av.y * bv.x; acc[1][4*j+1] += av.y * bv.y;
                acc[1][4*j+2] += av.y * bv.z; acc[1][4*j+3] += av.y * bv.w;
                acc[2][4*j+0] += av.z * bv.x; acc[2][4*j+1] += av.z * bv.y;
                acc[2][4*j+2] += av.z * bv.z; acc[2][4*j+3] += av.z * bv.w;
                acc[3][4*j+0] += av.w * bv.x; acc[3][4*j+1] += av.w * bv.y;
                acc[3][4*j+2] += av.w * bv.z; acc[3][4*j+3] += av.w * bv.w;
            }
        }
    }
    const float third = 1.f / 3.f;
    #pragma unroll
    for (int u = 0; u < 4; ++u) {
        int gr = r0 + tr + u;
        if (gr >= N_ENT) break;
        #pragma unroll
        for (int j = 0; j < 4; ++j) {
            float4 o;
            o.x = acc[u][4*j+0] * third;
            o.y = acc[u][4*j+1] * third;
            o.z = acc[u][4*j+2] * third;
            o.w = acc[u][4*j+3] * third;
            *(float4*)(out + (size_t)gr * HID + tt * 16 + j * 4) = o;
        }
    }
}

// ---------------- batchnorm stats: per-column sum & sumsq ----------------
__global__ void bn_stats(const float* __restrict__ out, float* __restrict__ stats) {
    int c = threadIdx.x;
    float s = 0.f, sq = 0.f;
    for (int r = blockIdx.x; r < N_ENT; r += gridDim.x) {
        float v = out[(size_t)r * HID + c];
        s += v; sq += v * v;
    }
    atomicAdd(&stats[c], s);
    atomicAdd(&stats[HID + c], sq);
}

// ---------------- batchnorm apply (population var) ----------------
__global__ void bn_apply(float* __restrict__ out, const float* __restrict__ stats,
                         const float* __restrict__ bnw, const float* __restrict__ bnb) {
    const float invN = 1.f / (float)N_ENT;
    const size_t total = (size_t)N_ENT * HID;
    for (size_t idx = (size_t)blockIdx.x * 256 + threadIdx.x; idx < total;
         idx += (size_t)gridDim.x * 256) {
        int c = (int)(idx & (HID - 1));
        float mean = stats[c] * invN;
        float var  = stats[HID + c] * invN - mean * mean;
        float v = (out[idx] - mean) * rsqrtf(var + BN_EPSF) * bnw[c] + bnb[c];
        out[idx] = v;
    }
}

// ---------------- rel_out = rel_embed @ w_rel  (loop_rel row is dropped by [:-1]) ----------------
__global__ void relout_kernel(const float* __restrict__ rel_embed,
                              const float* __restrict__ w_rel,
                              float* __restrict__ rel_out) {
    __shared__ float row[HID];
    int r = blockIdx.x;
    int c = threadIdx.x;
    row[c] = rel_embed[(size_t)r * HID + c];
    __syncthreads();
    float s = 0.f;
    for (int k = 0; k < HID; ++k) s += row[k] * w_rel[(size_t)k * HID + c];
    rel_out[(size_t)r * HID + c] = s;
}

extern "C" void kernel_launch(void* const* d_in, const int* in_sizes, int n_in,
                              void* d_out, int out_size, void* d_ws, size_t ws_size,
                              hipStream_t stream) {
    const float* x        = (const float*)d_in[0];
    const int*   ei       = (const int*)d_in[1];
    const int*   et       = (const int*)d_in[2];
    const float* rel      = (const float*)d_in[3];
    const float* w_loop   = (const float*)d_in[4];
    const float* w_in     = (const float*)d_in[5];
    const float* w_out    = (const float*)d_in[6];
    const float* w_rel    = (const float*)d_in[7];
    const float* loop_rel = (const float*)d_in[8];
    const float* bnw      = (const float*)d_in[9];
    const float* bnb      = (const float*)d_in[10];

    float* out     = (float*)d_out;
    float* rel_out = out + (size_t)N_ENT * HID;
    // acc_in reuses d_out (in-place GEMM, per-block row ownership). acc_out in ws.
    float* accA    = out;
    float* accB    = (float*)d_ws;
    float* deg_in  = accB + (size_t)N_ENT * HID;
    float* deg_out = deg_in + N_ENT;
    float* stats   = deg_out + N_ENT;

    hipMemsetAsync(d_out, 0, (size_t)out_size * sizeof(float), stream);
    hipMemsetAsync(d_ws, 0, ((size_t)N_ENT * HID + 2 * (size_t)N_ENT + 512) * sizeof(float), stream);

    deg_kernel<<<(TOT_E + 255) / 256, 256, 0, stream>>>(ei, deg_in, deg_out);
    scatter_kernel<<<TOT_E / 4, 256, 0, stream>>>(x, ei, et, rel, deg_in, deg_out, accA, accB);
    fused_gemm<<<(N_ENT + 63) / 64, 256, 0, stream>>>(accA, accB, x, loop_rel,
                                                      w_in, w_out, w_loop, out);
    bn_stats<<<1024, 256, 0, stream>>>(out, stats);
    bn_apply<<<2048, 256, 0, stream>>>(out, stats, bnw, bnb);
    relout_kernel<<<50, 256, 0, stream>>>(rel, w_rel, rel_out);
}

// Round 2
// 920.431 us; speedup vs baseline: 3.2190x; 3.2190x over previous
//
#include <hip/hip_runtime.h>

#define HID     256
#define N_ENT   100000
#define TOT_E   640000
#define HALF_E  320000
#define NSEG    (2 * N_ENT)
#define BN_EPSF 1e-5f
#define SCAN_ELEMS 1024
#define NBLK_SCAN  ((NSEG + SCAN_ELEMS - 1) / SCAN_ELEMS)   // 196

// ================= CSR build =================
__global__ void hist_kernel(const int* __restrict__ ei, int* __restrict__ offs) {
    int j = blockIdx.x * 256 + threadIdx.x;
    if (j >= TOT_E) return;
    int seg = ei[j] + ((j < HALF_E) ? 0 : N_ENT);
    atomicAdd(&offs[seg], 1);
}

__global__ __launch_bounds__(256) void scan1(int* __restrict__ offs, int* __restrict__ bsums) {
    __shared__ int tsum[256];
    int b = blockIdx.x, t = threadIdx.x;
    int base = b * SCAN_ELEMS + t * 4;
    int v[4] = {0, 0, 0, 0};
    if (base + 3 < NSEG) {
        int4 lv = *(const int4*)(offs + base);
        v[0] = lv.x; v[1] = lv.y; v[2] = lv.z; v[3] = lv.w;
    } else {
        for (int i = 0; i < 4; ++i) if (base + i < NSEG) v[i] = offs[base + i];
    }
    tsum[t] = v[0] + v[1] + v[2] + v[3];
    __syncthreads();
    for (int d = 1; d < 256; d <<= 1) {
        int val = (t >= d) ? tsum[t - d] : 0;
        __syncthreads();
        tsum[t] += val;
        __syncthreads();
    }
    int run = (t == 0) ? 0 : tsum[t - 1];
    if (t == 255) bsums[b] = tsum[255];
    int w[4];
    for (int i = 0; i < 4; ++i) { w[i] = run; run += v[i]; }
    if (base + 3 < NSEG) *(int4*)(offs + base) = make_int4(w[0], w[1], w[2], w[3]);
    else for (int i = 0; i < 4; ++i) if (base + i < NSEG) offs[base + i] = w[i];
}

__global__ void scan2(int* __restrict__ bsums) {
    __shared__ int tmp[256];
    int t = threadIdx.x;
    int v = (t < NBLK_SCAN) ? bsums[t] : 0;
    tmp[t] = v;
    __syncthreads();
    for (int d = 1; d < 256; d <<= 1) {
        int val = (t >= d) ? tmp[t - d] : 0;
        __syncthreads();
        tmp[t] += val;
        __syncthreads();
    }
    if (t < NBLK_SCAN) bsums[t] = (t == 0) ? 0 : tmp[t - 1];
}

__global__ __launch_bounds__(256) void scan3(int* __restrict__ offs, const int* __restrict__ bsums) {
    int b = blockIdx.x;
    int add = bsums[b];
    int base = b * SCAN_ELEMS + threadIdx.x * 4;
    if (base + 3 < NSEG) {
        int4 v = *(int4*)(offs + base);
        v.x += add; v.y += add; v.z += add; v.w += add;
        *(int4*)(offs + base) = v;
    } else {
        for (int i = 0; i < 4; ++i) if (base + i < NSEG) offs[base + i] += add;
    }
}

// fill: elist[pos] = col | (type << 17); mutates offs[s] -> segment END.
__global__ void fill_kernel(const int* __restrict__ ei, const int* __restrict__ et,
                            int* __restrict__ offs, int* __restrict__ elist) {
    int j = blockIdx.x * 256 + threadIdx.x;
    if (j >= TOT_E) return;
    int seg = ei[j] + ((j < HALF_E) ? 0 : N_ENT);
    int pos = atomicAdd(&offs[seg], 1);
    elist[pos] = ei[TOT_E + j] | (et[j] << 17);
}

// ================= gather: acc[r] = sum_e norm * x[col] * rel[t], one wave per segment, no atomics =================
__global__ __launch_bounds__(256) void gather_kernel(
        const float* __restrict__ x, const float* __restrict__ rel,
        const int* __restrict__ offs, const int* __restrict__ elist,
        float* __restrict__ accA, float* __restrict__ accB) {
    int s = blockIdx.x * 4 + (threadIdx.x >> 6);
    int lane = threadIdx.x & 63;
    int start = (s == 0) ? 0 : offs[s - 1];
    int end   = offs[s];
    int half_base = (s >= N_ENT) ? N_ENT : 0;
    int r = s - half_base;
    float4 a = make_float4(0.f, 0.f, 0.f, 0.f);
    if (end > start) {
        float inv_r = rsqrtf((float)(end - start));
        for (int e = start; e < end; ++e) {
            int p = elist[e];
            int c = p & 0x1FFFF;
            int t = p >> 17;
            int sc = half_base + c;
            int cs = (sc == 0) ? 0 : offs[sc - 1];
            int ce = offs[sc];
            if (ce > cs) {
                float norm = inv_r * rsqrtf((float)(ce - cs));
                float4 xv = *(const float4*)(x   + (size_t)c * HID + lane * 4);
                float4 rv = *(const float4*)(rel + (size_t)t * HID + lane * 4);
                a.x += xv.x * rv.x * norm;
                a.y += xv.y * rv.y * norm;
                a.z += xv.z * rv.z * norm;
                a.w += xv.w * rv.w * norm;
            }
        }
    }
    float* dst = ((s >= N_ENT) ? accB : accA) + (size_t)r * HID + lane * 4;
    *(float4*)dst = a;
}

// ================= fallback (round-1) atomic scatter =================
__global__ void deg_kernel(const int* __restrict__ ei, float* deg_in, float* deg_out) {
    int j = blockIdx.x * 256 + threadIdx.x;
    if (j >= TOT_E) return;
    atomicAdd((j < HALF_E ? deg_in : deg_out) + ei[j], 1.0f);
}

__global__ __launch_bounds__(256) void scatter_kernel(
        const float* __restrict__ x, const int* __restrict__ ei,
        const int* __restrict__ et, const float* __restrict__ rel,
        const float* __restrict__ deg_in, const float* __restrict__ deg_out,
        float* __restrict__ accA, float* __restrict__ accB) {
    int edge = blockIdx.x * 4 + (threadIdx.x >> 6);
    if (edge >= TOT_E) return;
    int lane = threadIdx.x & 63;
    bool is_in = edge < HALF_E;
    int row = ei[edge];
    int col = ei[TOT_E + edge];
    int t   = et[edge];
    const float* deg = is_in ? deg_in : deg_out;
    float dr = deg[row], dc = deg[col];
    float norm = (dr > 0.f ? rsqrtf(dr) : 0.f) * (dc > 0.f ? rsqrtf(dc) : 0.f);
    float* acc = (is_in ? accA : accB) + (size_t)row * HID + lane * 4;
    float4 xv = *(const float4*)(x   + (size_t)col * HID + lane * 4);
    float4 rv = *(const float4*)(rel + (size_t)t   * HID + lane * 4);
    atomicAdd(acc + 0, xv.x * rv.x * norm);
    atomicAdd(acc + 1, xv.y * rv.y * norm);
    atomicAdd(acc + 2, xv.z * rv.z * norm);
    atomicAdd(acc + 3, xv.w * rv.w * norm);
}

// ================= fused GEMM: out = [accA|accB|x*loop_rel] @ [w_in;w_out;w_loop] / 3 =================
__global__ __launch_bounds__(256) void fused_gemm(
        const float* __restrict__ accA, const float* __restrict__ accB,
        const float* __restrict__ x, const float* __restrict__ loop_rel,
        const float* __restrict__ w_in, const float* __restrict__ w_out,
        const float* __restrict__ w_loop, float* __restrict__ out)
{
    __shared__ float  AsT[32][68];
    __shared__ float4 Ws[32][4][16];
    const int tid = threadIdx.x;
    const int r0  = blockIdx.x * 64;
    const int tr  = (tid >> 4) << 2;
    const int tt  = tid & 15;
    float acc[4][16];
    #pragma unroll
    for (int u = 0; u < 4; ++u)
        #pragma unroll
        for (int j = 0; j < 16; ++j) acc[u][j] = 0.f;

    for (int kt = 0; kt < 24; ++kt) {
        const int src = kt >> 3;
        const int ks  = (kt & 7) << 5;
        const float* A = (src == 0) ? accA : ((src == 1) ? accB : x);
        const float* W = (src == 0) ? w_in : ((src == 1) ? w_out : w_loop);
        __syncthreads();
        #pragma unroll
        for (int i = 0; i < 2; ++i) {
            int f = tid + (i << 8);
            int row = f >> 3;
            int cf  = f & 7;
            int gr  = r0 + row;
            float4 v = make_float4(0.f, 0.f, 0.f, 0.f);
            if (gr < N_ENT) v = *(const float4*)(A + (size_t)gr * HID + ks + (cf << 2));
            if (src == 2) {
                float4 lr = *(const float4*)(loop_rel + ks + (cf << 2));
                v.x *= lr.x; v.y *= lr.y; v.z *= lr.z; v.w *= lr.w;
            }
            int k = cf << 2;
            AsT[k + 0][row] = v.x;
            AsT[k + 1][row] = v.y;
            AsT[k + 2][row] = v.z;
            AsT[k + 3][row] = v.w;
        }
        #pragma unroll
        for (int i = 0; i < 8; ++i) {
            int f  = tid + (i << 8);
            int kk = f >> 6;
            int g  = f & 63;
            float4 wv = *(const float4*)(W + (size_t)(ks + kk) * HID + (g << 2));
            Ws[kk][g & 3][g >> 2] = wv;
        }
        __syncthreads();
        #pragma unroll
        for (int kk = 0; kk < 32; ++kk) {
            float4 av = *(const float4*)(&AsT[kk][tr]);
            #pragma unroll
            for (int j = 0; j < 4; ++j) {
                float4 bv = Ws[kk][j][tt];
                acc[0][4*j+0] += av.x * bv.x; acc[0][4*j+1] += av.x * bv.y;
                acc[0][4*j+2] += av.x * bv.z; acc[0][4*j+3] += av.x * bv.w;
                acc[1][4*j+0] += av.y * bv.x; acc[1][4*j+1] += av.y * bv.y;
                acc[1][4*j+2] += av.y * bv.z; acc[1][4*j+3] += av.y * bv.w;
                acc[2][4*j+0] += av.z * bv.x; acc[2][4*j+1] += av.z * bv.y;
                acc[2][4*j+2] += av.z * bv.z; acc[2][4*j+3] += av.z * bv.w;
                acc[3][4*j+0] += av.w * bv.x; acc[3][4*j+1] += av.w * bv.y;
                acc[3][4*j+2] += av.w * bv.z; acc[3][4*j+3] += av.w * bv.w;
            }
        }
    }
    const float third = 1.f / 3.f;
    #pragma unroll
    for (int u = 0; u < 4; ++u) {
        int gr = r0 + tr + u;
        if (gr >= N_ENT) break;
        #pragma unroll
        for (int j = 0; j < 4; ++j) {
            float4 o;
            o.x = acc[u][4*j+0] * third;
            o.y = acc[u][4*j+1] * third;
            o.z = acc[u][4*j+2] * third;
            o.w = acc[u][4*j+3] * third;
            *(float4*)(out + (size_t)gr * HID + tt * 16 + j * 4) = o;
        }
    }
}

// ================= batchnorm =================
__global__ void bn_stats(const float* __restrict__ out, float* __restrict__ stats) {
    int c = threadIdx.x;
    float s = 0.f, sq = 0.f;
    for (int r = blockIdx.x; r < N_ENT; r += gridDim.x) {
        float v = out[(size_t)r * HID + c];
        s += v; sq += v * v;
    }
    atomicAdd(&stats[c], s);
    atomicAdd(&stats[HID + c], sq);
}

__global__ void bn_apply(float* __restrict__ out, const float* __restrict__ stats,
                         const float* __restrict__ bnw, const float* __restrict__ bnb) {
    const float invN = 1.f / (float)N_ENT;
    const size_t total = (size_t)N_ENT * HID;
    for (size_t idx = (size_t)blockIdx.x * 256 + threadIdx.x; idx < total;
         idx += (size_t)gridDim.x * 256) {
        int c = (int)(idx & (HID - 1));
        float mean = stats[c] * invN;
        float var  = stats[HID + c] * invN - mean * mean;
        out[idx] = (out[idx] - mean) * rsqrtf(var + BN_EPSF) * bnw[c] + bnb[c];
    }
}

// ================= rel_out = rel_embed @ w_rel =================
__global__ void relout_kernel(const float* __restrict__ rel_embed,
                              const float* __restrict__ w_rel,
                              float* __restrict__ rel_out) {
    __shared__ float row[HID];
    int r = blockIdx.x;
    int c = threadIdx.x;
    row[c] = rel_embed[(size_t)r * HID + c];
    __syncthreads();
    float s = 0.f;
    for (int k = 0; k < HID; ++k) s += row[k] * w_rel[(size_t)k * HID + c];
    rel_out[(size_t)r * HID + c] = s;
}

extern "C" void kernel_launch(void* const* d_in, const int* in_sizes, int n_in,
                              void* d_out, int out_size, void* d_ws, size_t ws_size,
                              hipStream_t stream) {
    const float* x        = (const float*)d_in[0];
    const int*   ei       = (const int*)d_in[1];
    const int*   et       = (const int*)d_in[2];
    const float* rel      = (const float*)d_in[3];
    const float* w_loop   = (const float*)d_in[4];
    const float* w_in     = (const float*)d_in[5];
    const float* w_out    = (const float*)d_in[6];
    const float* w_rel    = (const float*)d_in[7];
    const float* loop_rel = (const float*)d_in[8];
    const float* bnw      = (const float*)d_in[9];
    const float* bnb      = (const float*)d_in[10];

    float* out     = (float*)d_out;
    float* rel_out = out + (size_t)N_ENT * HID;
    float* accA    = out;                       // in-place GEMM, per-block row ownership
    float* accB    = (float*)d_ws;

    const size_t need_csr = ((size_t)N_ENT * HID + NSEG + TOT_E + 256 + 512) * sizeof(float);

    if (ws_size >= need_csr) {
        // ---- CSR + gather path (no float atomics in hot loop) ----
        int*   offs  = (int*)(accB + (size_t)N_ENT * HID);  // NSEG
        int*   elist = offs + NSEG;                          // TOT_E
        int*   bsums = elist + TOT_E;                        // 256
        float* stats = (float*)(bsums + 256);                // 512

        hipMemsetAsync(offs, 0, NSEG * sizeof(int), stream);
        hipMemsetAsync(stats, 0, 512 * sizeof(float), stream);

        hist_kernel<<<TOT_E / 256, 256, 0, stream>>>(ei, offs);
        scan1<<<NBLK_SCAN, 256, 0, stream>>>(offs, bsums);
        scan2<<<1, 256, 0, stream>>>(bsums);
        scan3<<<NBLK_SCAN, 256, 0, stream>>>(offs, bsums);
        fill_kernel<<<TOT_E / 256, 256, 0, stream>>>(ei, et, offs, elist);
        gather_kernel<<<NSEG / 4, 256, 0, stream>>>(x, rel, offs, elist, accA, accB);
        fused_gemm<<<(N_ENT + 63) / 64, 256, 0, stream>>>(accA, accB, x, loop_rel,
                                                          w_in, w_out, w_loop, out);
        bn_stats<<<1024, 256, 0, stream>>>(out, stats);
        bn_apply<<<2048, 256, 0, stream>>>(out, stats, bnw, bnb);
        relout_kernel<<<50, 256, 0, stream>>>(rel, w_rel, rel_out);
    } else {
        // ---- fallback: round-1 atomic scatter path ----
        float* deg_in  = accB + (size_t)N_ENT * HID;
        float* deg_out = deg_in + N_ENT;
        float* stats   = deg_out + N_ENT;

        hipMemsetAsync(d_out, 0, (size_t)out_size * sizeof(float), stream);
        hipMemsetAsync(d_ws, 0, ((size_t)N_ENT * HID + 2 * (size_t)N_ENT + 512) * sizeof(float), stream);

        deg_kernel<<<(TOT_E + 255) / 256, 256, 0, stream>>>(ei, deg_in, deg_out);
        scatter_kernel<<<TOT_E / 4, 256, 0, stream>>>(x, ei, et, rel, deg_in, deg_out, accA, accB);
        fused_gemm<<<(N_ENT + 63) / 64, 256, 0, stream>>>(accA, accB, x, loop_rel,
                                                          w_in, w_out, w_loop, out);
        bn_stats<<<1024, 256, 0, stream>>>(out, stats);
        bn_apply<<<2048, 256, 0, stream>>>(out, stats, bnw, bnb);
        relout_kernel<<<50, 256, 0, stream>>>(rel, w_rel, rel_out);
    }
}

// Round 3
// 375.827 us; speedup vs baseline: 7.8836x; 2.4491x over previous
//
#include <hip/hip_runtime.h>

#define HID     256
#define N_ENT   100000
#define TOT_E   640000
#define HALF_E  320000
#define NSEG    (2 * N_ENT)
#define BN_EPSF 1e-5f
#define SCAN_ELEMS 1024
#define NBLK_SCAN  ((NSEG + SCAN_ELEMS - 1) / SCAN_ELEMS)   // 196

typedef short bf16x8 __attribute__((ext_vector_type(8)));
typedef float f32x4  __attribute__((ext_vector_type(4)));

__device__ __forceinline__ short f2b(float f) {
    union { float f; unsigned u; } c; c.f = f;
    unsigned u = c.u;
    u += 0x7FFF + ((u >> 16) & 1);          // round-to-nearest-even
    return (short)(u >> 16);
}

// ================= CSR build =================
__global__ void hist_kernel(const int* __restrict__ ei, int* __restrict__ offs) {
    int j = blockIdx.x * 256 + threadIdx.x;
    if (j >= TOT_E) return;
    int seg = ei[j] + ((j < HALF_E) ? 0 : N_ENT);
    atomicAdd(&offs[seg], 1);
}

__global__ __launch_bounds__(256) void scan1(int* __restrict__ offs, int* __restrict__ bsums) {
    __shared__ int tsum[256];
    int b = blockIdx.x, t = threadIdx.x;
    int base = b * SCAN_ELEMS + t * 4;
    int v[4] = {0, 0, 0, 0};
    if (base + 3 < NSEG) {
        int4 lv = *(const int4*)(offs + base);
        v[0] = lv.x; v[1] = lv.y; v[2] = lv.z; v[3] = lv.w;
    } else {
        for (int i = 0; i < 4; ++i) if (base + i < NSEG) v[i] = offs[base + i];
    }
    tsum[t] = v[0] + v[1] + v[2] + v[3];
    __syncthreads();
    for (int d = 1; d < 256; d <<= 1) {
        int val = (t >= d) ? tsum[t - d] : 0;
        __syncthreads();
        tsum[t] += val;
        __syncthreads();
    }
    int run = (t == 0) ? 0 : tsum[t - 1];
    if (t == 255) bsums[b] = tsum[255];
    int w[4];
    for (int i = 0; i < 4; ++i) { w[i] = run; run += v[i]; }
    if (base + 3 < NSEG) *(int4*)(offs + base) = make_int4(w[0], w[1], w[2], w[3]);
    else for (int i = 0; i < 4; ++i) if (base + i < NSEG) offs[base + i] = w[i];
}

__global__ void scan2(int* __restrict__ bsums) {
    __shared__ int tmp[256];
    int t = threadIdx.x;
    int v = (t < NBLK_SCAN) ? bsums[t] : 0;
    tmp[t] = v;
    __syncthreads();
    for (int d = 1; d < 256; d <<= 1) {
        int val = (t >= d) ? tmp[t - d] : 0;
        __syncthreads();
        tmp[t] += val;
        __syncthreads();
    }
    if (t < NBLK_SCAN) bsums[t] = (t == 0) ? 0 : tmp[t - 1];
}

__global__ __launch_bounds__(256) void scan3(int* __restrict__ offs, const int* __restrict__ bsums) {
    int b = blockIdx.x;
    int add = bsums[b];
    int base = b * SCAN_ELEMS + threadIdx.x * 4;
    if (base + 3 < NSEG) {
        int4 v = *(int4*)(offs + base);
        v.x += add; v.y += add; v.z += add; v.w += add;
        *(int4*)(offs + base) = v;
    } else {
        for (int i = 0; i < 4; ++i) if (base + i < NSEG) offs[base + i] += add;
    }
}

// fill: elist[pos] = col | (type << 17); mutates offs[s] -> segment END.
__global__ void fill_kernel(const int* __restrict__ ei, const int* __restrict__ et,
                            int* __restrict__ offs, int* __restrict__ elist) {
    int j = blockIdx.x * 256 + threadIdx.x;
    if (j >= TOT_E) return;
    int seg = ei[j] + ((j < HALF_E) ? 0 : N_ENT);
    int pos = atomicAdd(&offs[seg], 1);
    elist[pos] = ei[TOT_E + j] | (et[j] << 17);
}

// ================= gather: one wave per segment, no atomics =================
__global__ __launch_bounds__(256) void gather_kernel(
        const float* __restrict__ x, const float* __restrict__ rel,
        const int* __restrict__ offs, const int* __restrict__ elist,
        float* __restrict__ accA, float* __restrict__ accB) {
    int s = blockIdx.x * 4 + (threadIdx.x >> 6);
    int lane = threadIdx.x & 63;
    int start = (s == 0) ? 0 : offs[s - 1];
    int end   = offs[s];
    int half_base = (s >= N_ENT) ? N_ENT : 0;
    int r = s - half_base;
    float4 a = make_float4(0.f, 0.f, 0.f, 0.f);
    if (end > start) {
        float inv_r = rsqrtf((float)(end - start));
        for (int e = start; e < end; ++e) {
            int p = elist[e];
            int c = p & 0x1FFFF;
            int t = p >> 17;
            int sc = half_base + c;
            int cs = (sc == 0) ? 0 : offs[sc - 1];
            int ce = offs[sc];
            if (ce > cs) {
                float norm = inv_r * rsqrtf((float)(ce - cs));
                float4 xv = *(const float4*)(x   + (size_t)c * HID + lane * 4);
                float4 rv = *(const float4*)(rel + (size_t)t * HID + lane * 4);
                a.x += xv.x * rv.x * norm;
                a.y += xv.y * rv.y * norm;
                a.z += xv.z * rv.z * norm;
                a.w += xv.w * rv.w * norm;
            }
        }
    }
    float* dst = ((s >= N_ENT) ? accB : accA) + (size_t)r * HID + lane * 4;
    *(float4*)dst = a;
}

// ================= WT = bf16 transpose of [w_in; w_out; diag(loop_rel) w_loop] =================
// WT[n][k], n in [0,256), k in [0,768)
__global__ void wcat_kernel(const float* __restrict__ w_in, const float* __restrict__ w_out,
                            const float* __restrict__ w_loop, const float* __restrict__ loop_rel,
                            short* __restrict__ WT) {
    int n = blockIdx.x;
    int t = threadIdx.x;
    float v0 = w_in  [(size_t)t * HID + n];
    float v1 = w_out [(size_t)t * HID + n];
    float v2 = w_loop[(size_t)t * HID + n] * loop_rel[t];
    short* row = WT + (size_t)n * 768;
    row[t]       = f2b(v0);
    row[256 + t] = f2b(v1);
    row[512 + t] = f2b(v2);
}

// ================= MFMA GEMM: out = [accA|accB|x] @ WT^T / 3, fused BN stats =================
// block: 256 threads = 4 waves; tile 64 rows x 256 cols; BK=64; 12 K-steps.
// LDS granule-swizzled: granule slot = g ^ (row&7), granule = 8 bf16 = 16B.
__global__ __launch_bounds__(256) void gemm_mfma(
        const float* __restrict__ accA, const float* __restrict__ accB,
        const float* __restrict__ x, const short* __restrict__ WT,
        float* __restrict__ out, float* __restrict__ stats)
{
    __shared__ __align__(16) short As[64 * 64];    // 8 KB
    __shared__ __align__(16) short Bs[256 * 64];   // 32 KB
    const int tid = threadIdx.x;
    const int l   = tid & 63;
    const int wid = tid >> 6;          // wave: N-range [wid*64, wid*64+64)
    const int r0  = blockIdx.x * 64;
    const int lr  = l & 15;
    const int lg  = l >> 4;            // 0..3

    f32x4 acc[4][4];
    #pragma unroll
    for (int i = 0; i < 4; ++i)
        #pragma unroll
        for (int j = 0; j < 4; ++j)
            acc[i][j] = (f32x4){0.f, 0.f, 0.f, 0.f};

    const int sg = tid & 7;            // staging granule column
    const int sr = tid >> 3;           // staging row base (0..31)

    for (int kt = 0; kt < 12; ++kt) {
        const int src = kt >> 2;
        const float* Ap = (src == 0) ? accA : ((src == 1) ? accB : x);
        const int ksg = kt * 64;           // k base in WT
        const int ksl = (kt & 3) * 64;     // k base within source (0..192)
        __syncthreads();
        // ---- A: 64 rows x 64 k, f32 -> bf16, swizzled ----
        #pragma unroll
        for (int h = 0; h < 2; ++h) {
            int r  = sr + 32 * h;
            int gr = r0 + r;
            float4 v0 = make_float4(0.f,0.f,0.f,0.f), v1 = v0;
            if (gr < N_ENT) {
                const float* p = Ap + (size_t)gr * HID + ksl + sg * 8;
                v0 = *(const float4*)p;
                v1 = *(const float4*)(p + 4);
            }
            bf16x8 pk;
            pk[0]=f2b(v0.x); pk[1]=f2b(v0.y); pk[2]=f2b(v0.z); pk[3]=f2b(v0.w);
            pk[4]=f2b(v1.x); pk[5]=f2b(v1.y); pk[6]=f2b(v1.z); pk[7]=f2b(v1.w);
            *(bf16x8*)&As[r * 64 + (sg ^ (r & 7)) * 8] = pk;
        }
        // ---- B: 256 rows (n) x 64 k from WT, swizzled ----
        #pragma unroll
        for (int i = 0; i < 8; ++i) {
            int n = sr + 32 * i;
            bf16x8 w = *(const bf16x8*)(WT + (size_t)n * 768 + ksg + sg * 8);
            *(bf16x8*)&Bs[n * 64 + (sg ^ (n & 7)) * 8] = w;
        }
        __syncthreads();
        // ---- compute: 2 k-chunks of 32, 16 MFMAs each ----
        #pragma unroll
        for (int kc = 0; kc < 2; ++kc) {
            const int gsel = kc * 4 + lg;
            bf16x8 af[4], bfr[4];
            #pragma unroll
            for (int i = 0; i < 4; ++i) {
                int r = 16 * i + lr;
                af[i] = *(const bf16x8*)&As[r * 64 + (gsel ^ (r & 7)) * 8];
            }
            #pragma unroll
            for (int j = 0; j < 4; ++j) {
                int n = wid * 64 + 16 * j + lr;
                bfr[j] = *(const bf16x8*)&Bs[n * 64 + (gsel ^ (n & 7)) * 8];
            }
            #pragma unroll
            for (int i = 0; i < 4; ++i)
                #pragma unroll
                for (int j = 0; j < 4; ++j)
                    acc[i][j] = __builtin_amdgcn_mfma_f32_16x16x32_bf16(
                                    af[i], bfr[j], acc[i][j], 0, 0, 0);
        }
    }

    // ---- epilogue: write out/3, fused BN partial stats ----
    const float third = 1.f / 3.f;
    float s[4]  = {0.f, 0.f, 0.f, 0.f};
    float sq[4] = {0.f, 0.f, 0.f, 0.f};
    #pragma unroll
    for (int i = 0; i < 4; ++i) {
        #pragma unroll
        for (int v = 0; v < 4; ++v) {
            int grow = r0 + 16 * i + lg * 4 + v;
            if (grow < N_ENT) {
                #pragma unroll
                for (int j = 0; j < 4; ++j) {
                    float val = acc[i][j][v] * third;
                    out[(size_t)grow * HID + wid * 64 + 16 * j + lr] = val;
                    s[j] += val; sq[j] += val * val;
                }
            }
        }
    }
    #pragma unroll
    for (int j = 0; j < 4; ++j) {
        s[j]  += __shfl_xor(s[j], 16);  s[j]  += __shfl_xor(s[j], 32);
        sq[j] += __shfl_xor(sq[j], 16); sq[j] += __shfl_xor(sq[j], 32);
    }
    if (lg == 0) {
        #pragma unroll
        for (int j = 0; j < 4; ++j) {
            int c = wid * 64 + 16 * j + lr;
            atomicAdd(&stats[c], s[j]);
            atomicAdd(&stats[HID + c], sq[j]);
        }
    }
}

// ================= batchnorm apply (population var) =================
__global__ void bn_apply(float* __restrict__ out, const float* __restrict__ stats,
                         const float* __restrict__ bnw, const float* __restrict__ bnb) {
    const float invN = 1.f / (float)N_ENT;
    const size_t total = (size_t)N_ENT * HID;
    for (size_t idx = (size_t)blockIdx.x * 256 + threadIdx.x; idx < total;
         idx += (size_t)gridDim.x * 256) {
        int c = (int)(idx & (HID - 1));
        float mean = stats[c] * invN;
        float var  = stats[HID + c] * invN - mean * mean;
        out[idx] = (out[idx] - mean) * rsqrtf(var + BN_EPSF) * bnw[c] + bnb[c];
    }
}

// ================= rel_out = rel_embed @ w_rel =================
__global__ void relout_kernel(const float* __restrict__ rel_embed,
                              const float* __restrict__ w_rel,
                              float* __restrict__ rel_out) {
    __shared__ float row[HID];
    int r = blockIdx.x;
    int c = threadIdx.x;
    row[c] = rel_embed[(size_t)r * HID + c];
    __syncthreads();
    float s = 0.f;
    for (int k = 0; k < HID; ++k) s += row[k] * w_rel[(size_t)k * HID + c];
    rel_out[(size_t)r * HID + c] = s;
}

extern "C" void kernel_launch(void* const* d_in, const int* in_sizes, int n_in,
                              void* d_out, int out_size, void* d_ws, size_t ws_size,
                              hipStream_t stream) {
    const float* x        = (const float*)d_in[0];
    const int*   ei       = (const int*)d_in[1];
    const int*   et       = (const int*)d_in[2];
    const float* rel      = (const float*)d_in[3];
    const float* w_loop   = (const float*)d_in[4];
    const float* w_in     = (const float*)d_in[5];
    const float* w_out    = (const float*)d_in[6];
    const float* w_rel    = (const float*)d_in[7];
    const float* loop_rel = (const float*)d_in[8];
    const float* bnw      = (const float*)d_in[9];
    const float* bnb      = (const float*)d_in[10];

    float* out     = (float*)d_out;
    float* rel_out = out + (size_t)N_ENT * HID;
    float* accA    = out;                       // in-place GEMM, per-block row ownership
    float* accB    = (float*)d_ws;

    int*   offs  = (int*)(accB + (size_t)N_ENT * HID);   // NSEG ints
    int*   elist = offs + NSEG;                           // TOT_E ints
    short* WT    = (short*)elist;                         // aliases elist AFTER gather (196608 bf16)
    int*   bsums = elist + TOT_E;                         // 256
    float* stats = (float*)(bsums + 256);                 // 512

    hipMemsetAsync(offs, 0, NSEG * sizeof(int), stream);
    hipMemsetAsync(stats, 0, 512 * sizeof(float), stream);

    hist_kernel<<<TOT_E / 256, 256, 0, stream>>>(ei, offs);
    scan1<<<NBLK_SCAN, 256, 0, stream>>>(offs, bsums);
    scan2<<<1, 256, 0, stream>>>(bsums);
    scan3<<<NBLK_SCAN, 256, 0, stream>>>(offs, bsums);
    fill_kernel<<<TOT_E / 256, 256, 0, stream>>>(ei, et, offs, elist);
    gather_kernel<<<NSEG / 4, 256, 0, stream>>>(x, rel, offs, elist, accA, accB);
    // elist/offs dead from here; WT overwrites elist (stream-ordered).
    wcat_kernel<<<256, 256, 0, stream>>>(w_in, w_out, w_loop, loop_rel, WT);
    gemm_mfma<<<(N_ENT + 63) / 64, 256, 0, stream>>>(accA, accB, x, WT, out, stats);
    bn_apply<<<2048, 256, 0, stream>>>(out, stats, bnw, bnb);
    relout_kernel<<<50, 256, 0, stream>>>(rel, w_rel, rel_out);
}

// Round 4
// 315.807 us; speedup vs baseline: 9.3819x; 1.1901x over previous
//
#include <hip/hip_runtime.h>

#define HID     256
#define N_ENT   100000
#define TOT_E   640000
#define HALF_E  320000
#define NSEG    (2 * N_ENT)
#define BN_EPSF 1e-5f
#define SCAN_ELEMS 1024
#define NBLK_SCAN  ((NSEG + SCAN_ELEMS - 1) / SCAN_ELEMS)   // 196

typedef short bf16x8 __attribute__((ext_vector_type(8)));
typedef short bf16x4 __attribute__((ext_vector_type(4)));
typedef float f32x4  __attribute__((ext_vector_type(4)));

__device__ __forceinline__ short f2b(float f) {
    union { float f; unsigned u; } c; c.f = f;
    unsigned u = c.u;
    u += 0x7FFF + ((u >> 16) & 1);          // round-to-nearest-even
    return (short)(u >> 16);
}
__device__ __forceinline__ float b2f(short b) {
    union { unsigned u; float f; } c;
    c.u = ((unsigned)(unsigned short)b) << 16;
    return c.f;
}

// ================= CSR build =================
__global__ void hist_kernel(const int* __restrict__ ei, int* __restrict__ offs) {
    int j = blockIdx.x * 256 + threadIdx.x;
    if (j >= TOT_E) return;
    int seg = ei[j] + ((j < HALF_E) ? 0 : N_ENT);
    atomicAdd(&offs[seg], 1);
}

__global__ void rnorm_kernel(const int* __restrict__ offs, float* __restrict__ rnorm) {
    int s = blockIdx.x * 256 + threadIdx.x;
    if (s >= NSEG) return;
    int c = offs[s];
    rnorm[s] = (c > 0) ? rsqrtf((float)c) : 0.f;
}

__global__ __launch_bounds__(256) void scan1(int* __restrict__ offs, int* __restrict__ bsums) {
    __shared__ int tsum[256];
    int b = blockIdx.x, t = threadIdx.x;
    int base = b * SCAN_ELEMS + t * 4;
    int v[4] = {0, 0, 0, 0};
    if (base + 3 < NSEG) {
        int4 lv = *(const int4*)(offs + base);
        v[0] = lv.x; v[1] = lv.y; v[2] = lv.z; v[3] = lv.w;
    } else {
        for (int i = 0; i < 4; ++i) if (base + i < NSEG) v[i] = offs[base + i];
    }
    tsum[t] = v[0] + v[1] + v[2] + v[3];
    __syncthreads();
    for (int d = 1; d < 256; d <<= 1) {
        int val = (t >= d) ? tsum[t - d] : 0;
        __syncthreads();
        tsum[t] += val;
        __syncthreads();
    }
    int run = (t == 0) ? 0 : tsum[t - 1];
    if (t == 255) bsums[b] = tsum[255];
    int w[4];
    for (int i = 0; i < 4; ++i) { w[i] = run; run += v[i]; }
    if (base + 3 < NSEG) *(int4*)(offs + base) = make_int4(w[0], w[1], w[2], w[3]);
    else for (int i = 0; i < 4; ++i) if (base + i < NSEG) offs[base + i] = w[i];
}

__global__ void scan2(int* __restrict__ bsums) {
    __shared__ int tmp[256];
    int t = threadIdx.x;
    int v = (t < NBLK_SCAN) ? bsums[t] : 0;
    tmp[t] = v;
    __syncthreads();
    for (int d = 1; d < 256; d <<= 1) {
        int val = (t >= d) ? tmp[t - d] : 0;
        __syncthreads();
        tmp[t] += val;
        __syncthreads();
    }
    if (t < NBLK_SCAN) bsums[t] = (t == 0) ? 0 : tmp[t - 1];
}

__global__ __launch_bounds__(256) void scan3(int* __restrict__ offs, const int* __restrict__ bsums) {
    int b = blockIdx.x;
    int add = bsums[b];
    int base = b * SCAN_ELEMS + threadIdx.x * 4;
    if (base + 3 < NSEG) {
        int4 v = *(int4*)(offs + base);
        v.x += add; v.y += add; v.z += add; v.w += add;
        *(int4*)(offs + base) = v;
    } else {
        for (int i = 0; i < 4; ++i) if (base + i < NSEG) offs[base + i] += add;
    }
}

// fill8: elist8[pos] = {col | type<<17, norm}; mutates offs[s] -> segment END.
__global__ void fill8_kernel(const int* __restrict__ ei, const int* __restrict__ et,
                             int* __restrict__ offs, const float* __restrict__ rnorm,
                             int2* __restrict__ elist8) {
    int j = blockIdx.x * 256 + threadIdx.x;
    if (j >= TOT_E) return;
    int hb  = (j < HALF_E) ? 0 : N_ENT;
    int seg = ei[j] + hb;
    int col = ei[TOT_E + j];
    float norm = rnorm[seg] * rnorm[hb + col];
    int pos = atomicAdd(&offs[seg], 1);
    elist8[pos] = make_int2(col | (et[j] << 17), __float_as_int(norm));
}

// fill (fallback): elist[pos] = col | (type << 17)
__global__ void fill_kernel(const int* __restrict__ ei, const int* __restrict__ et,
                            int* __restrict__ offs, int* __restrict__ elist) {
    int j = blockIdx.x * 256 + threadIdx.x;
    if (j >= TOT_E) return;
    int seg = ei[j] + ((j < HALF_E) ? 0 : N_ENT);
    int pos = atomicAdd(&offs[seg], 1);
    elist[pos] = ei[TOT_E + j] | (et[j] << 17);
}

// ================= f32 -> bf16 bulk convert =================
__global__ void tobf16_kernel(const float* __restrict__ src, short* __restrict__ dst, int n8) {
    int i = blockIdx.x * 256 + threadIdx.x;
    if (i >= n8) return;
    const float4* p = (const float4*)(src + (size_t)i * 8);
    float4 v0 = p[0], v1 = p[1];
    bf16x8 pk;
    pk[0]=f2b(v0.x); pk[1]=f2b(v0.y); pk[2]=f2b(v0.z); pk[3]=f2b(v0.w);
    pk[4]=f2b(v1.x); pk[5]=f2b(v1.y); pk[6]=f2b(v1.z); pk[7]=f2b(v1.w);
    *(bf16x8*)(dst + (size_t)i * 8) = pk;
}

// ================= gather (bf16 plane): one wave per segment, unroll x2 =================
__global__ __launch_bounds__(256) void gather_h(
        const short* __restrict__ xh, const short* __restrict__ relh,
        const int* __restrict__ offs, const int2* __restrict__ elist8,
        short* __restrict__ accA, short* __restrict__ accB) {
    int s = blockIdx.x * 4 + (threadIdx.x >> 6);
    int lane = threadIdx.x & 63;
    int start = (s == 0) ? 0 : offs[s - 1];
    int end   = offs[s];
    float ax0=0.f, ay0=0.f, az0=0.f, aw0=0.f;
    float ax1=0.f, ay1=0.f, az1=0.f, aw1=0.f;
    int e = start;
    for (; e + 2 <= end; e += 2) {
        int2 p0 = elist8[e];
        int2 p1 = elist8[e + 1];
        int   c0 = p0.x & 0x1FFFF, t0 = p0.x >> 17;
        float n0 = __int_as_float(p0.y);
        int   c1 = p1.x & 0x1FFFF, t1 = p1.x >> 17;
        float n1 = __int_as_float(p1.y);
        bf16x4 xv0 = *(const bf16x4*)(xh   + (size_t)c0 * HID + lane * 4);
        bf16x4 rv0 = *(const bf16x4*)(relh + (size_t)t0 * HID + lane * 4);
        bf16x4 xv1 = *(const bf16x4*)(xh   + (size_t)c1 * HID + lane * 4);
        bf16x4 rv1 = *(const bf16x4*)(relh + (size_t)t1 * HID + lane * 4);
        ax0 += b2f(xv0[0]) * b2f(rv0[0]) * n0;
        ay0 += b2f(xv0[1]) * b2f(rv0[1]) * n0;
        az0 += b2f(xv0[2]) * b2f(rv0[2]) * n0;
        aw0 += b2f(xv0[3]) * b2f(rv0[3]) * n0;
        ax1 += b2f(xv1[0]) * b2f(rv1[0]) * n1;
        ay1 += b2f(xv1[1]) * b2f(rv1[1]) * n1;
        az1 += b2f(xv1[2]) * b2f(rv1[2]) * n1;
        aw1 += b2f(xv1[3]) * b2f(rv1[3]) * n1;
    }
    if (e < end) {
        int2 p = elist8[e];
        int   c = p.x & 0x1FFFF, t = p.x >> 17;
        float n = __int_as_float(p.y);
        bf16x4 xv = *(const bf16x4*)(xh   + (size_t)c * HID + lane * 4);
        bf16x4 rv = *(const bf16x4*)(relh + (size_t)t * HID + lane * 4);
        ax0 += b2f(xv[0]) * b2f(rv[0]) * n;
        ay0 += b2f(xv[1]) * b2f(rv[1]) * n;
        az0 += b2f(xv[2]) * b2f(rv[2]) * n;
        aw0 += b2f(xv[3]) * b2f(rv[3]) * n;
    }
    int hb = (s >= N_ENT) ? N_ENT : 0;
    short* dst = ((s >= N_ENT) ? accB : accA) + (size_t)(s - hb) * HID + lane * 4;
    bf16x4 pk;
    pk[0] = f2b(ax0 + ax1); pk[1] = f2b(ay0 + ay1);
    pk[2] = f2b(az0 + az1); pk[3] = f2b(aw0 + aw1);
    *(bf16x4*)dst = pk;
}

// ================= gather (fallback, f32 plane) =================
__global__ __launch_bounds__(256) void gather_kernel(
        const float* __restrict__ x, const float* __restrict__ rel,
        const int* __restrict__ offs, const int* __restrict__ elist,
        float* __restrict__ accA, float* __restrict__ accB) {
    int s = blockIdx.x * 4 + (threadIdx.x >> 6);
    int lane = threadIdx.x & 63;
    int start = (s == 0) ? 0 : offs[s - 1];
    int end   = offs[s];
    int half_base = (s >= N_ENT) ? N_ENT : 0;
    int r = s - half_base;
    float4 a = make_float4(0.f, 0.f, 0.f, 0.f);
    if (end > start) {
        float inv_r = rsqrtf((float)(end - start));
        for (int e = start; e < end; ++e) {
            int p = elist[e];
            int c = p & 0x1FFFF;
            int t = p >> 17;
            int sc = half_base + c;
            int cs = (sc == 0) ? 0 : offs[sc - 1];
            int ce = offs[sc];
            if (ce > cs) {
                float norm = inv_r * rsqrtf((float)(ce - cs));
                float4 xv = *(const float4*)(x   + (size_t)c * HID + lane * 4);
                float4 rv = *(const float4*)(rel + (size_t)t * HID + lane * 4);
                a.x += xv.x * rv.x * norm;
                a.y += xv.y * rv.y * norm;
                a.z += xv.z * rv.z * norm;
                a.w += xv.w * rv.w * norm;
            }
        }
    }
    float* dst = ((s >= N_ENT) ? accB : accA) + (size_t)r * HID + lane * 4;
    *(float4*)dst = a;
}

// ================= WT = bf16 transpose of [w_in; w_out; diag(loop_rel) w_loop] =================
__global__ void wcat_kernel(const float* __restrict__ w_in, const float* __restrict__ w_out,
                            const float* __restrict__ w_loop, const float* __restrict__ loop_rel,
                            short* __restrict__ WT) {
    int n = blockIdx.x;
    int t = threadIdx.x;
    float v0 = w_in  [(size_t)t * HID + n];
    float v1 = w_out [(size_t)t * HID + n];
    float v2 = w_loop[(size_t)t * HID + n] * loop_rel[t];
    short* row = WT + (size_t)n * 768;
    row[t]       = f2b(v0);
    row[256 + t] = f2b(v1);
    row[512 + t] = f2b(v2);
}

// ================= MFMA GEMM (bf16 A sources) =================
__global__ __launch_bounds__(256) void gemm_mfma_h(
        const short* __restrict__ accA, const short* __restrict__ accB,
        const short* __restrict__ xh, const short* __restrict__ WT,
        float* __restrict__ out, float* __restrict__ stats)
{
    __shared__ __align__(16) short As[64 * 64];    // 8 KB
    __shared__ __align__(16) short Bs[256 * 64];   // 32 KB
    const int tid = threadIdx.x;
    const int l   = tid & 63;
    const int wid = tid >> 6;
    const int r0  = blockIdx.x * 64;
    const int lr  = l & 15;
    const int lg  = l >> 4;

    f32x4 acc[4][4];
    #pragma unroll
    for (int i = 0; i < 4; ++i)
        #pragma unroll
        for (int j = 0; j < 4; ++j)
            acc[i][j] = (f32x4){0.f, 0.f, 0.f, 0.f};

    const int sg = tid & 7;
    const int sr = tid >> 3;

    for (int kt = 0; kt < 12; ++kt) {
        const int src = kt >> 2;
        const short* Ap = (src == 0) ? accA : ((src == 1) ? accB : xh);
        const int ksg = kt * 64;
        const int ksl = (kt & 3) * 64;
        __syncthreads();
        #pragma unroll
        for (int h = 0; h < 2; ++h) {
            int r  = sr + 32 * h;
            int gr = r0 + r;
            bf16x8 v = {0,0,0,0,0,0,0,0};
            if (gr < N_ENT) v = *(const bf16x8*)(Ap + (size_t)gr * HID + ksl + sg * 8);
            *(bf16x8*)&As[r * 64 + (sg ^ (r & 7)) * 8] = v;
        }
        #pragma unroll
        for (int i = 0; i < 8; ++i) {
            int n = sr + 32 * i;
            bf16x8 w = *(const bf16x8*)(WT + (size_t)n * 768 + ksg + sg * 8);
            *(bf16x8*)&Bs[n * 64 + (sg ^ (n & 7)) * 8] = w;
        }
        __syncthreads();
        #pragma unroll
        for (int kc = 0; kc < 2; ++kc) {
            const int gsel = kc * 4 + lg;
            bf16x8 af[4], bfr[4];
            #pragma unroll
            for (int i = 0; i < 4; ++i) {
                int r = 16 * i + lr;
                af[i] = *(const bf16x8*)&As[r * 64 + (gsel ^ (r & 7)) * 8];
            }
            #pragma unroll
            for (int j = 0; j < 4; ++j) {
                int n = wid * 64 + 16 * j + lr;
                bfr[j] = *(const bf16x8*)&Bs[n * 64 + (gsel ^ (n & 7)) * 8];
            }
            #pragma unroll
            for (int i = 0; i < 4; ++i)
                #pragma unroll
                for (int j = 0; j < 4; ++j)
                    acc[i][j] = __builtin_amdgcn_mfma_f32_16x16x32_bf16(
                                    af[i], bfr[j], acc[i][j], 0, 0, 0);
        }
    }

    const float third = 1.f / 3.f;
    float s[4]  = {0.f, 0.f, 0.f, 0.f};
    float sq[4] = {0.f, 0.f, 0.f, 0.f};
    #pragma unroll
    for (int i = 0; i < 4; ++i) {
        #pragma unroll
        for (int v = 0; v < 4; ++v) {
            int grow = r0 + 16 * i + lg * 4 + v;
            if (grow < N_ENT) {
                #pragma unroll
                for (int j = 0; j < 4; ++j) {
                    float val = acc[i][j][v] * third;
                    out[(size_t)grow * HID + wid * 64 + 16 * j + lr] = val;
                    s[j] += val; sq[j] += val * val;
                }
            }
        }
    }
    #pragma unroll
    for (int j = 0; j < 4; ++j) {
        s[j]  += __shfl_xor(s[j], 16);  s[j]  += __shfl_xor(s[j], 32);
        sq[j] += __shfl_xor(sq[j], 16); sq[j] += __shfl_xor(sq[j], 32);
    }
    if (lg == 0) {
        #pragma unroll
        for (int j = 0; j < 4; ++j) {
            int c = wid * 64 + 16 * j + lr;
            atomicAdd(&stats[c], s[j]);
            atomicAdd(&stats[HID + c], sq[j]);
        }
    }
}

// ================= MFMA GEMM (fallback, f32 A sources) =================
__global__ __launch_bounds__(256) void gemm_mfma(
        const float* __restrict__ accA, const float* __restrict__ accB,
        const float* __restrict__ x, const short* __restrict__ WT,
        float* __restrict__ out, float* __restrict__ stats)
{
    __shared__ __align__(16) short As[64 * 64];
    __shared__ __align__(16) short Bs[256 * 64];
    const int tid = threadIdx.x;
    const int l   = tid & 63;
    const int wid = tid >> 6;
    const int r0  = blockIdx.x * 64;
    const int lr  = l & 15;
    const int lg  = l >> 4;

    f32x4 acc[4][4];
    #pragma unroll
    for (int i = 0; i < 4; ++i)
        #pragma unroll
        for (int j = 0; j < 4; ++j)
            acc[i][j] = (f32x4){0.f, 0.f, 0.f, 0.f};

    const int sg = tid & 7;
    const int sr = tid >> 3;

    for (int kt = 0; kt < 12; ++kt) {
        const int src = kt >> 2;
        const float* Ap = (src == 0) ? accA : ((src == 1) ? accB : x);
        const int ksg = kt * 64;
        const int ksl = (kt & 3) * 64;
        __syncthreads();
        #pragma unroll
        for (int h = 0; h < 2; ++h) {
            int r  = sr + 32 * h;
            int gr = r0 + r;
            float4 v0 = make_float4(0.f,0.f,0.f,0.f), v1 = v0;
            if (gr < N_ENT) {
                const float* p = Ap + (size_t)gr * HID + ksl + sg * 8;
                v0 = *(const float4*)p;
                v1 = *(const float4*)(p + 4);
            }
            bf16x8 pk;
            pk[0]=f2b(v0.x); pk[1]=f2b(v0.y); pk[2]=f2b(v0.z); pk[3]=f2b(v0.w);
            pk[4]=f2b(v1.x); pk[5]=f2b(v1.y); pk[6]=f2b(v1.z); pk[7]=f2b(v1.w);
            *(bf16x8*)&As[r * 64 + (sg ^ (r & 7)) * 8] = pk;
        }
        #pragma unroll
        for (int i = 0; i < 8; ++i) {
            int n = sr + 32 * i;
            bf16x8 w = *(const bf16x8*)(WT + (size_t)n * 768 + ksg + sg * 8);
            *(bf16x8*)&Bs[n * 64 + (sg ^ (n & 7)) * 8] = w;
        }
        __syncthreads();
        #pragma unroll
        for (int kc = 0; kc < 2; ++kc) {
            const int gsel = kc * 4 + lg;
            bf16x8 af[4], bfr[4];
            #pragma unroll
            for (int i = 0; i < 4; ++i) {
                int r = 16 * i + lr;
                af[i] = *(const bf16x8*)&As[r * 64 + (gsel ^ (r & 7)) * 8];
            }
            #pragma unroll
            for (int j = 0; j < 4; ++j) {
                int n = wid * 64 + 16 * j + lr;
                bfr[j] = *(const bf16x8*)&Bs[n * 64 + (gsel ^ (n & 7)) * 8];
            }
            #pragma unroll
            for (int i = 0; i < 4; ++i)
                #pragma unroll
                for (int j = 0; j < 4; ++j)
                    acc[i][j] = __builtin_amdgcn_mfma_f32_16x16x32_bf16(
                                    af[i], bfr[j], acc[i][j], 0, 0, 0);
        }
    }

    const float third = 1.f / 3.f;
    float s[4]  = {0.f, 0.f, 0.f, 0.f};
    float sq[4] = {0.f, 0.f, 0.f, 0.f};
    #pragma unroll
    for (int i = 0; i < 4; ++i) {
        #pragma unroll
        for (int v = 0; v < 4; ++v) {
            int grow = r0 + 16 * i + lg * 4 + v;
            if (grow < N_ENT) {
                #pragma unroll
                for (int j = 0; j < 4; ++j) {
                    float val = acc[i][j][v] * third;
                    out[(size_t)grow * HID + wid * 64 + 16 * j + lr] = val;
                    s[j] += val; sq[j] += val * val;
                }
            }
        }
    }
    #pragma unroll
    for (int j = 0; j < 4; ++j) {
        s[j]  += __shfl_xor(s[j], 16);  s[j]  += __shfl_xor(s[j], 32);
        sq[j] += __shfl_xor(sq[j], 16); sq[j] += __shfl_xor(sq[j], 32);
    }
    if (lg == 0) {
        #pragma unroll
        for (int j = 0; j < 4; ++j) {
            int c = wid * 64 + 16 * j + lr;
            atomicAdd(&stats[c], s[j]);
            atomicAdd(&stats[HID + c], sq[j]);
        }
    }
}

// ================= batchnorm apply (vectorized, population var) =================
__global__ void bn_apply(float* __restrict__ out, const float* __restrict__ stats,
                         const float* __restrict__ bnw, const float* __restrict__ bnb) {
    const float invN = 1.f / (float)N_ENT;
    const int total4 = N_ENT * (HID / 4);
    for (int i = blockIdx.x * 256 + threadIdx.x; i < total4; i += gridDim.x * 256) {
        int c = (i & 63) * 4;
        float4 v = *(float4*)(out + (size_t)i * 4);
        #pragma unroll
        for (int k = 0; k < 4; ++k) {
            float mean = stats[c + k] * invN;
            float var  = stats[HID + c + k] * invN - mean * mean;
            float sc   = rsqrtf(var + BN_EPSF) * bnw[c + k];
            float sh   = bnb[c + k] - mean * sc;
            float* comp = (k == 0) ? &v.x : (k == 1) ? &v.y : (k == 2) ? &v.z : &v.w;
            *comp = (*comp) * sc + sh;
        }
        *(float4*)(out + (size_t)i * 4) = v;
    }
}

// ================= rel_out = rel_embed @ w_rel =================
__global__ void relout_kernel(const float* __restrict__ rel_embed,
                              const float* __restrict__ w_rel,
                              float* __restrict__ rel_out) {
    __shared__ float row[HID];
    int r = blockIdx.x;
    int c = threadIdx.x;
    row[c] = rel_embed[(size_t)r * HID + c];
    __syncthreads();
    float s = 0.f;
    for (int k = 0; k < HID; ++k) s += row[k] * w_rel[(size_t)k * HID + c];
    rel_out[(size_t)r * HID + c] = s;
}

extern "C" void kernel_launch(void* const* d_in, const int* in_sizes, int n_in,
                              void* d_out, int out_size, void* d_ws, size_t ws_size,
                              hipStream_t stream) {
    const float* x        = (const float*)d_in[0];
    const int*   ei       = (const int*)d_in[1];
    const int*   et       = (const int*)d_in[2];
    const float* rel      = (const float*)d_in[3];
    const float* w_loop   = (const float*)d_in[4];
    const float* w_in     = (const float*)d_in[5];
    const float* w_out    = (const float*)d_in[6];
    const float* w_rel    = (const float*)d_in[7];
    const float* loop_rel = (const float*)d_in[8];
    const float* bnw      = (const float*)d_in[9];
    const float* bnb      = (const float*)d_in[10];

    float* out     = (float*)d_out;
    float* rel_out = out + (size_t)N_ENT * HID;

    // ---- big (bf16-plane) layout ----
    const size_t XH_B   = (size_t)N_ENT * HID * 2;   // 51.2 MB
    const size_t ACC_B  = (size_t)N_ENT * HID * 2;   // 51.2 MB each
    const size_t OFFS_B = (size_t)NSEG * 4;
    const size_t EL8_B  = (size_t)TOT_E * 8;
    const size_t RN_B   = (size_t)NSEG * 4;
    const size_t need_big = XH_B + 2 * ACC_B + OFFS_B + EL8_B + RN_B
                          + 256 * 4 + 512 * 4 + (size_t)50 * HID * 2;

    if (ws_size >= need_big) {
        char* w = (char*)d_ws;
        short* xh     = (short*)w;              w += XH_B;
        short* accA_h = (short*)w;              w += ACC_B;
        short* accB_h = (short*)w;              w += ACC_B;
        int*   offs   = (int*)w;                w += OFFS_B;
        int2*  elist8 = (int2*)w;               short* WT = (short*)w;   w += EL8_B;
        float* rnorm  = (float*)w;              w += RN_B;
        int*   bsums  = (int*)w;                w += 256 * 4;
        float* stats  = (float*)w;              w += 512 * 4;
        short* relh   = (short*)w;

        hipMemsetAsync(offs, 0, OFFS_B, stream);
        hipMemsetAsync(stats, 0, 512 * 4, stream);

        tobf16_kernel<<<(N_ENT * HID / 8 + 255) / 256, 256, 0, stream>>>(x, xh, N_ENT * HID / 8);
        tobf16_kernel<<<(50 * HID / 8 + 255) / 256, 256, 0, stream>>>(rel, relh, 50 * HID / 8);
        hist_kernel<<<TOT_E / 256, 256, 0, stream>>>(ei, offs);
        rnorm_kernel<<<(NSEG + 255) / 256, 256, 0, stream>>>(offs, rnorm);
        scan1<<<NBLK_SCAN, 256, 0, stream>>>(offs, bsums);
        scan2<<<1, 256, 0, stream>>>(bsums);
        scan3<<<NBLK_SCAN, 256, 0, stream>>>(offs, bsums);
        fill8_kernel<<<TOT_E / 256, 256, 0, stream>>>(ei, et, offs, rnorm, elist8);
        gather_h<<<NSEG / 4, 256, 0, stream>>>(xh, relh, offs, elist8, accA_h, accB_h);
        // elist8 dead; WT aliases it (stream-ordered).
        wcat_kernel<<<256, 256, 0, stream>>>(w_in, w_out, w_loop, loop_rel, WT);
        gemm_mfma_h<<<(N_ENT + 63) / 64, 256, 0, stream>>>(accA_h, accB_h, xh, WT, out, stats);
        bn_apply<<<2048, 256, 0, stream>>>(out, stats, bnw, bnb);
        relout_kernel<<<50, 256, 0, stream>>>(rel, w_rel, rel_out);
    } else {
        // ---- fallback: round-3 f32 CSR path (known-good) ----
        float* accA    = out;
        float* accB    = (float*)d_ws;
        int*   offs  = (int*)(accB + (size_t)N_ENT * HID);
        int*   elist = offs + NSEG;
        short* WT    = (short*)elist;
        int*   bsums = elist + TOT_E;
        float* stats = (float*)(bsums + 256);

        hipMemsetAsync(offs, 0, NSEG * sizeof(int), stream);
        hipMemsetAsync(stats, 0, 512 * sizeof(float), stream);

        hist_kernel<<<TOT_E / 256, 256, 0, stream>>>(ei, offs);
        scan1<<<NBLK_SCAN, 256, 0, stream>>>(offs, bsums);
        scan2<<<1, 256, 0, stream>>>(bsums);
        scan3<<<NBLK_SCAN, 256, 0, stream>>>(offs, bsums);
        fill_kernel<<<TOT_E / 256, 256, 0, stream>>>(ei, et, offs, elist);
        gather_kernel<<<NSEG / 4, 256, 0, stream>>>(x, rel, offs, elist, accA, accB);
        wcat_kernel<<<256, 256, 0, stream>>>(w_in, w_out, w_loop, loop_rel, WT);
        gemm_mfma<<<(N_ENT + 63) / 64, 256, 0, stream>>>(accA, accB, x, WT, out, stats);
        bn_apply<<<2048, 256, 0, stream>>>(out, stats, bnw, bnb);
        relout_kernel<<<50, 256, 0, stream>>>(rel, w_rel, rel_out);
    }
}